// Round 9
// baseline (106.063 us; speedup 1.0000x reference)
//
#include <hip/hip_runtime.h>
#include <hip/hip_bf16.h>
#include <stdint.h>

#define SEQ     4096
#define HIDDEN  640
#define HDIM    80
#define NH      8
#define NKV     2
#define WINDOW  512
#define SINK    4
#define BQ      64
#define BK      64
#define KSTR    104   // Ks row stride (bf16): 2-way banks on b128 reads
#define VSTR    72    // Vt/Pl row stride (bf16): 2-way banks

typedef __bf16 bf16x8 __attribute__((ext_vector_type(8)));
typedef float  f32x4  __attribute__((ext_vector_type(4)));

__device__ inline __bf16 f2bf(float f) {
    union { float f; uint32_t u; } x; x.f = f;
    uint32_t r = x.u + 0x7FFF + ((x.u >> 16) & 1);   // RNE, no NaN inputs
    union { unsigned short s; __bf16 b; } y; y.s = (unsigned short)(r >> 16);
    return y.b;
}
__device__ inline float bf2f(unsigned short u) {
    union { uint32_t u; float f; } c; c.u = ((uint32_t)u) << 16; return c.f;
}
__device__ inline float fexp2(float x) {
#if __has_builtin(__builtin_amdgcn_exp2f)
    return __builtin_amdgcn_exp2f(x);
#else
    return exp2f(x);
#endif
}

// ---------------------------------------------------------------------------
// Fused prep: x -> bf16 (blocks [0,2560)) + all weight transposes
// (blocks [2560,3560), 32x32 tiles).
// ---------------------------------------------------------------------------
__global__ __launch_bounds__(256) void prep_kernel(
    const float* __restrict__ x, const float* __restrict__ Wq,
    const float* __restrict__ Wk, const float* __restrict__ Wv,
    const float* __restrict__ Wo, __bf16* __restrict__ xb,
    __bf16* __restrict__ WqkvT, __bf16* __restrict__ WoT)
{
    const int flat = blockIdx.x;
    const int tid  = threadIdx.x;
    if (flat < 2560) {
        int i = flat * 256 + tid;
        const float4 v = *(const float4*)&x[4 * i];
        xb[4 * i + 0] = f2bf(v.x);
        xb[4 * i + 1] = f2bf(v.y);
        xb[4 * i + 2] = f2bf(v.z);
        xb[4 * i + 3] = f2bf(v.w);
        return;
    }
    const int wf = flat - 2560;
    const float* src;
    __bf16* dstb;
    int idx, tiles_x, N;
    if (wf < 400)      { src = Wq; dstb = WqkvT;             idx = wf;       tiles_x = 20; N = 640; }
    else if (wf < 500) { src = Wk; dstb = WqkvT + 640 * 640; idx = wf - 400; tiles_x = 5;  N = 160; }
    else if (wf < 600) { src = Wv; dstb = WqkvT + 800 * 640; idx = wf - 500; tiles_x = 5;  N = 160; }
    else               { src = Wo; dstb = WoT;               idx = wf - 600; tiles_x = 20; N = 640; }
    const int n0 = (idx % tiles_x) * 32;
    const int k0 = (idx / tiles_x) * 32;

    __shared__ float t[32][33];
    const int tx = tid & 31, ty = tid >> 5;     // 32 x 8
    #pragma unroll
    for (int i = 0; i < 4; ++i) {
        int r = ty + 8 * i;
        t[r][tx] = src[(size_t)(k0 + r) * N + n0 + tx];
    }
    __syncthreads();
    #pragma unroll
    for (int i = 0; i < 4; ++i) {
        int r = ty + 8 * i;
        dstb[(size_t)(n0 + r) * 640 + k0 + tx] = f2bf(t[tx][r]);
    }
}

// ---------------------------------------------------------------------------
// MFMA bf16 GEMM, 2-step-ahead prefetch pipeline. 512 threads = 8 waves
// (2M x 4N), tile 128x128, BK=32, dbuf LDS, 1 barrier/step.
// At step ks: issue loads for ks+2 (into the just-freed set), MFMA on
// buf[ks&1], write set loaded at ks-1 (data for ks+1) into buf[ks&1 ^ 1].
// Requires nk even (K % 64 == 0).
// ---------------------------------------------------------------------------
template <typename OutT>
__global__ __launch_bounds__(512) void gemm_bf16_mfma(
    const __bf16* __restrict__ A, const __bf16* __restrict__ BT,
    OutT* __restrict__ C, int M, int N, int K, int ldc)
{
    __shared__ __bf16 As[2][128][40];
    __shared__ __bf16 Bs[2][128][40];
    const int BUFE = 128 * 40;

    const int tid  = threadIdx.x;
    const int wave = tid >> 6;
    const int lane = tid & 63;
    const int wr = wave >> 2, wc = wave & 3;
    const int l15 = lane & 15, lq = lane >> 4;
    const int m0 = blockIdx.y * 128, n0 = blockIdx.x * 128;

    f32x4 acc[4][2];
    #pragma unroll
    for (int m = 0; m < 4; ++m)
        #pragma unroll
        for (int n = 0; n < 2; ++n) acc[m][n] = (f32x4)0.0f;

    const int sArr  = tid >> 8;
    const int sc    = tid & 255;
    const int srow  = sc >> 1;
    const int shalf = sc & 1;
    const __bf16* gsrc = sArr ? BT : A;
    const int     grow = sArr ? n0 : m0;
    const size_t  g0   = (size_t)(grow + srow) * K + 16 * shalf;
    __bf16* ldst = (sArr ? &Bs[0][0][0] : &As[0][0][0]) + srow * 40 + 16 * shalf;

    const int nk = K >> 5;

    // prologue: step0 -> LDS buf0 (via set X), step1 -> set Y
    bf16x8 x0 = *(const bf16x8*)&gsrc[g0];
    bf16x8 x1 = *(const bf16x8*)&gsrc[g0 + 8];
    *(bf16x8*)ldst       = x0;
    *(bf16x8*)(ldst + 8) = x1;
    bf16x8 y0, y1;
    if (1 < nk) {
        y0 = *(const bf16x8*)&gsrc[g0 + 32];
        y1 = *(const bf16x8*)&gsrc[g0 + 40];
    }
    __syncthreads();

#define GEMM_STEP(CUR, L0, L1, W0, W1, KS)                                     \
    {                                                                          \
        if ((KS) + 2 < nk) {                                                   \
            L0 = *(const bf16x8*)&gsrc[g0 + (size_t)((KS) + 2) * 32];          \
            L1 = *(const bf16x8*)&gsrc[g0 + (size_t)((KS) + 2) * 32 + 8];      \
        }                                                                      \
        bf16x8 af[4], bfr[2];                                                  \
        _Pragma("unroll")                                                      \
        for (int m = 0; m < 4; ++m)                                            \
            af[m] = *(const bf16x8*)&As[CUR][wr * 64 + m * 16 + l15][8 * lq];  \
        _Pragma("unroll")                                                      \
        for (int n = 0; n < 2; ++n)                                            \
            bfr[n] = *(const bf16x8*)&Bs[CUR][wc * 32 + n * 16 + l15][8 * lq]; \
        __builtin_amdgcn_s_setprio(1);                                         \
        _Pragma("unroll")                                                      \
        for (int m = 0; m < 4; ++m)                                            \
            _Pragma("unroll")                                                  \
            for (int n = 0; n < 2; ++n)                                        \
                acc[m][n] = __builtin_amdgcn_mfma_f32_16x16x32_bf16(           \
                    af[m], bfr[n], acc[m][n], 0, 0, 0);                        \
        __builtin_amdgcn_s_setprio(0);                                         \
        if ((KS) + 1 < nk) {                                                   \
            *(bf16x8*)(ldst + (1 - (CUR)) * BUFE)     = W0;                    \
            *(bf16x8*)(ldst + (1 - (CUR)) * BUFE + 8) = W1;                    \
        }                                                                      \
        __syncthreads();                                                       \
    }

    for (int ks = 0; ks < nk; ks += 2) {
        GEMM_STEP(0, x0, x1, y0, y1, ks);       // even: read buf0, write Y, load X
        GEMM_STEP(1, y0, y1, x0, x1, ks + 1);   // odd:  read buf1, write X, load Y
    }
#undef GEMM_STEP

    #pragma unroll
    for (int m = 0; m < 4; ++m) {
        #pragma unroll
        for (int n = 0; n < 2; ++n) {
            const int col = n0 + wc * 32 + n * 16 + l15;
            if (col < N) {
                const int rbase = m0 + wr * 64 + m * 16 + 4 * lq;
                #pragma unroll
                for (int r = 0; r < 4; ++r) {
                    if constexpr (sizeof(OutT) == 2)
                        C[(size_t)(rbase + r) * ldc + col] = f2bf(acc[m][n][r]);
                    else
                        C[(size_t)(rbase + r) * ldc + col] = acc[m][n][r];
                }
            }
        }
    }
}

// ---------------------------------------------------------------------------
// RMSNorm + RoPE: one block per row, 10 heads looped (unchanged from r8).
// ---------------------------------------------------------------------------
__global__ __launch_bounds__(128) void norm_rope_kernel(
    const unsigned short* __restrict__ qkvb, const float* __restrict__ cosb,
    const float* __restrict__ sinb, const float* __restrict__ qw,
    const float* __restrict__ kw, __bf16* __restrict__ qb,
    __bf16* __restrict__ kb)
{
    const int row = blockIdx.x;
    const int tid = threadIdx.x;
    __shared__ float red[2];

    float c = 0.f, s = 0.f, wqv = 0.f, wkv = 0.f;
    if (tid < HDIM) {
        c   = cosb[(size_t)row * (HDIM / 2) + (tid >> 1)];
        s   = sinb[(size_t)row * (HDIM / 2) + (tid >> 1)];
        wqv = qw[tid];
        wkv = kw[tid];
    }
    const float sgn = (tid & 1) ? 1.0f : -1.0f;
    const float QSCALE = 0.11180339887498948f * 1.4426950408889634f;

    for (int hh = 0; hh < 10; ++hh) {
        const unsigned short* p = (hh < NH)
            ? qkvb + (size_t)row * 960 + hh * HDIM
            : qkvb + (size_t)row * 960 + HIDDEN + (hh - NH) * HDIM;
        float v = (tid < HDIM) ? bf2f(p[tid]) : 0.0f;
        float sq = v * v;
        #pragma unroll
        for (int off = 32; off; off >>= 1) sq += __shfl_down(sq, off);
        if ((tid & 63) == 0) red[tid >> 6] = sq;
        __syncthreads();
        float rms = rsqrtf((red[0] + red[1]) * (1.0f / HDIM) + 1e-5f);

        float w  = (hh < NH) ? wqv : wkv;
        float vn = v * rms * w;
        float vp = __shfl_xor(vn, 1);
        float o  = vn * c + sgn * vp * s;

        if (tid < HDIM) {
            if (hh < NH) qb[(size_t)row * HIDDEN + hh * HDIM + tid] = (__bf16)(o * QSCALE);
            else         kb[(size_t)row * (NKV * HDIM) + (hh - NH) * HDIM + tid] = (__bf16)o;
        }
        __syncthreads();
    }
}

// ---------------------------------------------------------------------------
// V transpose: vtb[kvh][d][seq] = panel v cols (bf16 bit copy).
// ---------------------------------------------------------------------------
__global__ __launch_bounds__(256) void v_transpose(
    const unsigned short* __restrict__ qkvb, unsigned short* __restrict__ vtb)
{
    __shared__ unsigned short t[32][33];
    const int s0 = blockIdx.x * 32;
    const int c0 = blockIdx.y * 32;
    const int tx = threadIdx.x, ty = threadIdx.y;
    #pragma unroll
    for (int i = 0; i < 4; ++i)
        t[ty + 8 * i][tx] = qkvb[(size_t)(s0 + ty + 8 * i) * 960 + 800 + c0 + tx];
    __syncthreads();
    #pragma unroll
    for (int i = 0; i < 4; ++i) {
        int g = c0 + ty + 8 * i;           // 0..159
        int kvh = g / HDIM, d = g % HDIM;
        vtb[((size_t)kvh * HDIM + d) * SEQ + s0 + tx] = t[tx][ty + 8 * i];
    }
}

// ---------------------------------------------------------------------------
// MFMA flash attention v4: single-buffered Ks/Vt, 2 barriers/tile,
// TWO-tile-ahead register prefetch (sets A/B), sink-tile fast path,
// exp2-domain softmax with exact skip-rescale. qb pre-scaled by scale*log2e.
// Per tile t: [load t+2 -> loadset] S -> bar1 -> write K(t+1) from writeset
//             -> softmax -> PV -> bar2 -> write V(t+1) from writeset.
// ---------------------------------------------------------------------------
__global__ __launch_bounds__(256) void flash_attn_mfma(
    const __bf16* __restrict__ qb, const __bf16* __restrict__ kb,
    const __bf16* __restrict__ vtb, __bf16* __restrict__ attnb)
{
    const int i0   = blockIdx.x * BQ;
    const int h    = blockIdx.y;
    const int kvh  = h >> 2;
    const int tid  = threadIdx.x;
    const int w    = tid >> 6;
    const int lane = tid & 63;
    const int l15  = lane & 15;
    const int lq   = lane >> 4;

    __shared__ __bf16 Ks[BK][KSTR];      // 13312 B
    __shared__ __bf16 Vt[HDIM][VSTR];    // 11520 B
    __shared__ __bf16 Pl[BQ][VSTR];      //  9216 B

    if (tid < 128) {
        int r = tid >> 1, c = HDIM + 8 * (tid & 1);
        *(float4*)&Ks[r][c] = make_float4(0.f, 0.f, 0.f, 0.f);
    }

    int koff[3], voff[3];
    bool act[3];
    #pragma unroll
    for (int i = 0; i < 3; ++i) {
        int c = tid + 256 * i;
        act[i] = (c < 640);
        int cc = act[i] ? c : 0;
        koff[i] = (cc / 10) * (NKV * HDIM) + 8 * (cc % 10);
        voff[i] = (cc >> 3) * SEQ + 8 * (cc & 7);
    }
    const __bf16* kbase = kb + kvh * HDIM;
    const __bf16* vbase = vtb + (size_t)kvh * HDIM * SEQ;
    __bf16* ksdst[3];
    __bf16* vsdst[3];
    #pragma unroll
    for (int i = 0; i < 3; ++i) {
        int cc = act[i] ? (tid + 256 * i) : 0;
        ksdst[i] = &Ks[cc / 10][8 * (cc % 10)];
        vsdst[i] = &Vt[cc >> 3][8 * (cc & 7)];
    }

    bf16x8 qf[3];
    {
        const __bf16* qrow = qb + (size_t)(i0 + 16 * w + l15) * HIDDEN + h * HDIM;
        #pragma unroll
        for (int ks = 0; ks < 3; ++ks) {
            int off = 32 * ks + 8 * lq;
            if (off >= HDIM) off = 0;     // dummy: multiplied by zeroed K pad
            qf[ks] = *(const bf16x8*)&qrow[off];
        }
    }

    float m_i[4], l_i[4];
    f32x4 o[5];
    #pragma unroll
    for (int r = 0; r < 4; ++r) { m_i[r] = -1e30f; l_i[r] = 0.0f; }
    #pragma unroll
    for (int n = 0; n < 5; ++n) o[n] = (f32x4)0.0f;

    const int w_lo   = i0 - (WINDOW - 1);
    const int w_tile = (w_lo <= 0) ? 0 : (w_lo & ~(BK - 1));
    const int n_win  = (i0 - w_tile) / BK + 1;
    const int n_tiles = n_win + ((w_tile > 0) ? 1 : 0);

    // prologue: tile0 -> LDS (through set A), tile1 -> set B
    bf16x8 krgA[3], vrgA[3], krgB[3], vrgB[3];
    #pragma unroll
    for (int i = 0; i < 3; ++i) {
        if (act[i]) {
            krgA[i] = *(const bf16x8*)&kbase[(size_t)w_tile * (NKV * HDIM) + koff[i]];
            vrgA[i] = *(const bf16x8*)&vbase[(size_t)w_tile + voff[i]];
        }
    }
    #pragma unroll
    for (int i = 0; i < 3; ++i) {
        if (act[i]) {
            *(bf16x8*)ksdst[i] = krgA[i];
            *(bf16x8*)vsdst[i] = vrgA[i];
        }
    }
    if (1 < n_tiles) {
        const int j1 = (1 < n_win) ? (w_tile + BK) : 0;
        #pragma unroll
        for (int i = 0; i < 3; ++i) {
            if (act[i]) {
                krgB[i] = *(const bf16x8*)&kbase[(size_t)j1 * (NKV * HDIM) + koff[i]];
                vrgB[i] = *(const bf16x8*)&vbase[(size_t)j1 + voff[i]];
            }
        }
    }
    __syncthreads();

#define FLASH_TILE(T, KLD, VLD, KWR, VWR)                                       \
    {                                                                           \
        const int  t_   = (T);                                                  \
        const int  j0_  = (t_ < n_win) ? (w_tile + t_ * BK) : 0;                \
        const bool sink_ = (t_ >= n_win);                                       \
        const bool more_ = (t_ + 1 < n_tiles);                                  \
        if (t_ + 2 < n_tiles) {                                                 \
            const int j2_ = (t_ + 2 < n_win) ? (w_tile + (t_ + 2) * BK) : 0;    \
            _Pragma("unroll")                                                   \
            for (int i = 0; i < 3; ++i) if (act[i]) {                           \
                KLD[i] = *(const bf16x8*)&kbase[(size_t)j2_ * (NKV*HDIM) + koff[i]]; \
                VLD[i] = *(const bf16x8*)&vbase[(size_t)j2_ + voff[i]];         \
            }                                                                   \
        }                                                                       \
        f32x4 sacc[4];                                                          \
        _Pragma("unroll")                                                       \
        for (int n = 0; n < 4; ++n) sacc[n] = (f32x4)0.0f;                      \
        __builtin_amdgcn_s_setprio(1);                                          \
        if (sink_) {                                                            \
            _Pragma("unroll")                                                   \
            for (int ks = 0; ks < 3; ++ks) {                                    \
                bf16x8 kf = *(const bf16x8*)&Ks[l15][32 * ks + 8 * lq];         \
                sacc[0] = __builtin_amdgcn_mfma_f32_16x16x32_bf16(qf[ks], kf, sacc[0], 0, 0, 0); \
            }                                                                   \
        } else {                                                                \
            _Pragma("unroll")                                                   \
            for (int ks = 0; ks < 3; ++ks) {                                    \
                _Pragma("unroll")                                               \
                for (int n = 0; n < 4; ++n) {                                   \
                    bf16x8 kf = *(const bf16x8*)&Ks[n * 16 + l15][32 * ks + 8 * lq]; \
                    sacc[n] = __builtin_amdgcn_mfma_f32_16x16x32_bf16(qf[ks], kf, sacc[n], 0, 0, 0); \
                }                                                               \
            }                                                                   \
        }                                                                       \
        __builtin_amdgcn_s_setprio(0);                                          \
        __syncthreads();                   /* bar1: S reads of Ks done */       \
        if (more_) {                                                            \
            _Pragma("unroll")                                                   \
            for (int i = 0; i < 3; ++i)                                         \
                if (act[i]) *(bf16x8*)ksdst[i] = KWR[i];                        \
        }                                                                       \
        const bool full_ = (j0_ >= i0 - 448) && (j0_ <= i0 - 64);               \
        if (!full_) {                                                           \
            const int nf_ = sink_ ? 1 : 4;                                      \
            _Pragma("unroll")                                                   \
            for (int n = 0; n < 4; ++n) {                                       \
                if (n >= nf_) break;                                            \
                int j = j0_ + 16 * n + l15;                                     \
                _Pragma("unroll")                                               \
                for (int r = 0; r < 4; ++r) {                                   \
                    int i = i0 + 16 * w + 4 * lq + r;                           \
                    bool allowed = (j <= i) && ((j >= i - (WINDOW - 1)) || (j < SINK)); \
                    if (!allowed) sacc[n][r] = -1e30f;                          \
                }                                                               \
            }                                                                   \
        }                                                                       \
        if (sink_) {                                                            \
            _Pragma("unroll")                                                   \
            for (int r = 0; r < 4; ++r) {                                       \
                float rmax = sacc[0][r];                                        \
                rmax = fmaxf(rmax, __shfl_xor(rmax, 1));                        \
                rmax = fmaxf(rmax, __shfl_xor(rmax, 2));                        \
                rmax = fmaxf(rmax, __shfl_xor(rmax, 4));                        \
                rmax = fmaxf(rmax, __shfl_xor(rmax, 8));                        \
                if (rmax > m_i[r]) {                                            \
                    float alpha = fexp2(m_i[r] - rmax);                         \
                    m_i[r] = rmax; l_i[r] *= alpha;                             \
                    _Pragma("unroll")                                           \
                    for (int n = 0; n < 5; ++n) o[n][r] *= alpha;               \
                }                                                               \
                float pe = fexp2(sacc[0][r] - m_i[r]);                          \
                Pl[16 * w + 4 * lq + r][l15]      = (__bf16)pe;                 \
                Pl[16 * w + 4 * lq + r][16 + l15] = (__bf16)0.0f;               \
                float rsum = pe;                                                \
                rsum += __shfl_xor(rsum, 1);                                    \
                rsum += __shfl_xor(rsum, 2);                                    \
                rsum += __shfl_xor(rsum, 4);                                    \
                rsum += __shfl_xor(rsum, 8);                                    \
                l_i[r] += rsum;                                                 \
            }                                                                   \
        } else {                                                                \
            _Pragma("unroll")                                                   \
            for (int r = 0; r < 4; ++r) {                                       \
                float rmax = fmaxf(fmaxf(sacc[0][r], sacc[1][r]), fmaxf(sacc[2][r], sacc[3][r])); \
                rmax = fmaxf(rmax, __shfl_xor(rmax, 1));                        \
                rmax = fmaxf(rmax, __shfl_xor(rmax, 2));                        \
                rmax = fmaxf(rmax, __shfl_xor(rmax, 4));                        \
                rmax = fmaxf(rmax, __shfl_xor(rmax, 8));                        \
                if (rmax > m_i[r]) {                                            \
                    float alpha = fexp2(m_i[r] - rmax);                         \
                    m_i[r] = rmax; l_i[r] *= alpha;                             \
                    _Pragma("unroll")                                           \
                    for (int n = 0; n < 5; ++n) o[n][r] *= alpha;               \
                }                                                               \
                float rsum = 0.0f;                                              \
                _Pragma("unroll")                                               \
                for (int n = 0; n < 4; ++n) {                                   \
                    float pe = fexp2(sacc[n][r] - m_i[r]);                      \
                    Pl[16 * w + 4 * lq + r][16 * n + l15] = (__bf16)pe;         \
                    rsum += pe;                                                 \
                }                                                               \
                rsum += __shfl_xor(rsum, 1);                                    \
                rsum += __shfl_xor(rsum, 2);                                    \
                rsum += __shfl_xor(rsum, 4);                                    \
                rsum += __shfl_xor(rsum, 8);                                    \
                l_i[r] += rsum;                                                 \
            }                                                                   \
        }                                                                       \
        __builtin_amdgcn_s_setprio(1);                                          \
        if (sink_) {                                                            \
            bf16x8 pf = *(const bf16x8*)&Pl[16 * w + l15][8 * lq];              \
            _Pragma("unroll")                                                   \
            for (int n = 0; n < 5; ++n) {                                       \
                bf16x8 vf = *(const bf16x8*)&Vt[16 * n + l15][8 * lq];          \
                o[n] = __builtin_amdgcn_mfma_f32_16x16x32_bf16(pf, vf, o[n], 0, 0, 0); \
            }                                                                   \
        } else {                                                                \
            _Pragma("unroll")                                                   \
            for (int ks = 0; ks < 2; ++ks) {                                    \
                bf16x8 pf = *(const bf16x8*)&Pl[16 * w + l15][32 * ks + 8 * lq]; \
                _Pragma("unroll")                                               \
                for (int n = 0; n < 5; ++n) {                                   \
                    bf16x8 vf = *(const bf16x8*)&Vt[16 * n + l15][32 * ks + 8 * lq]; \
                    o[n] = __builtin_amdgcn_mfma_f32_16x16x32_bf16(pf, vf, o[n], 0, 0, 0); \
                }                                                               \
            }                                                                   \
        }                                                                       \
        __builtin_amdgcn_s_setprio(0);                                          \
        __syncthreads();                   /* bar2: PV reads of Vt done */      \
        if (more_) {                                                            \
            _Pragma("unroll")                                                   \
            for (int i = 0; i < 3; ++i)                                         \
                if (act[i]) *(bf16x8*)vsdst[i] = VWR[i];                        \
        }                                                                       \
    }

    for (int t = 0; t < n_tiles; t += 2) {
        FLASH_TILE(t, krgA, vrgA, krgB, vrgB);          // load->A, write B(t+1)
        if (t + 1 < n_tiles)
            FLASH_TILE(t + 1, krgB, vrgB, krgA, vrgA);  // load->B, write A(t+2)
    }
#undef FLASH_TILE

    // ---- epilogue ----
    #pragma unroll
    for (int r = 0; r < 4; ++r) {
        float inv = 1.0f / l_i[r];
        int row = i0 + 16 * w + 4 * lq + r;
        #pragma unroll
        for (int n = 0; n < 5; ++n)
            attnb[(size_t)row * HIDDEN + h * HDIM + 16 * n + l15] = (__bf16)(o[n][r] * inv);
    }
}

// ---------------------------------------------------------------------------
extern "C" void kernel_launch(void* const* d_in, const int* in_sizes, int n_in,
                              void* d_out, int out_size, void* d_ws, size_t ws_size,
                              hipStream_t stream)
{
    const float* x    = (const float*)d_in[0];
    const float* cosb = (const float*)d_in[1];
    const float* sinb = (const float*)d_in[2];
    const float* Wq   = (const float*)d_in[3];
    const float* Wk   = (const float*)d_in[4];
    const float* Wv   = (const float*)d_in[5];
    const float* Wo   = (const float*)d_in[6];
    const float* qw   = (const float*)d_in[7];
    const float* kw   = (const float*)d_in[8];
    float* out = (float*)d_out;

    char* ws = (char*)d_ws;
    __bf16* qkvb  = (__bf16*)ws;                                 // [4096][960]
    __bf16* xb    = qkvb + (size_t)SEQ * 960;                    // [4096][640] -> attnb
    __bf16* qb    = xb   + (size_t)SEQ * HIDDEN;                 // [4096][640]
    __bf16* kb    = qb   + (size_t)SEQ * HIDDEN;                 // [4096][160]
    __bf16* vtb   = kb   + (size_t)SEQ * 160;                    // [2][80][4096]
    __bf16* WqkvT = vtb  + (size_t)2 * HDIM * SEQ;               // [1024][640]
    __bf16* WoT   = WqkvT + (size_t)1024 * HIDDEN;               // [640][640]

    prep_kernel<<<dim3(3560), dim3(256), 0, stream>>>(
        x, Wq, Wk, Wv, Wo, xb, WqkvT, WoT);

    gemm_bf16_mfma<__bf16><<<dim3(8, SEQ / 128), dim3(512), 0, stream>>>(
        xb, WqkvT, qkvb, SEQ, 960, HIDDEN, 960);

    norm_rope_kernel<<<dim3(SEQ), dim3(128), 0, stream>>>(
        (const unsigned short*)qkvb, cosb, sinb, qw, kw, qb, kb);

    v_transpose<<<dim3(SEQ / 32, 160 / 32), dim3(32, 8), 0, stream>>>(
        (const unsigned short*)qkvb, (unsigned short*)vtb);

    flash_attn_mfma<<<dim3(SEQ / BQ, NH), dim3(256), 0, stream>>>(
        qb, kb, vtb, xb);

    gemm_bf16_mfma<float><<<dim3(HIDDEN / 128, SEQ / 128), dim3(512), 0, stream>>>(
        xb, WoT, out, SEQ, HIDDEN, HIDDEN, HIDDEN);
}

// Round 10
// 89.332 us; speedup vs baseline: 1.1873x; 1.1873x over previous
//
#include <hip/hip_runtime.h>
#include <hip/hip_bf16.h>
#include <stdint.h>

#define SEQ     4096
#define HIDDEN  640
#define HDIM    80
#define NH      8
#define NKV     2
#define WINDOW  512
#define SINK    4
#define BQ      32    // flash q-tile (2 waves per block)
#define BK      64
#define KSTR    104   // Ks row stride (bf16): 2-way banks on b128 reads
#define VSTR    72    // Vt/Pl row stride (bf16): 2-way banks

typedef __bf16 bf16x8 __attribute__((ext_vector_type(8)));
typedef float  f32x4  __attribute__((ext_vector_type(4)));

__device__ inline __bf16 f2bf(float f) {
    union { float f; uint32_t u; } x; x.f = f;
    uint32_t r = x.u + 0x7FFF + ((x.u >> 16) & 1);   // RNE, no NaN inputs
    union { unsigned short s; __bf16 b; } y; y.s = (unsigned short)(r >> 16);
    return y.b;
}
__device__ inline float bf2f(unsigned short u) {
    union { uint32_t u; float f; } c; c.u = ((uint32_t)u) << 16; return c.f;
}
__device__ inline float fexp2(float x) {
#if __has_builtin(__builtin_amdgcn_exp2f)
    return __builtin_amdgcn_exp2f(x);
#else
    return exp2f(x);
#endif
}

// ---------------------------------------------------------------------------
// Fused prep: x -> bf16 (blocks [0,2560)) + all weight transposes
// (blocks [2560,3560), 32x32 tiles).
// ---------------------------------------------------------------------------
__global__ __launch_bounds__(256) void prep_kernel(
    const float* __restrict__ x, const float* __restrict__ Wq,
    const float* __restrict__ Wk, const float* __restrict__ Wv,
    const float* __restrict__ Wo, __bf16* __restrict__ xb,
    __bf16* __restrict__ WqkvT, __bf16* __restrict__ WoT)
{
    const int flat = blockIdx.x;
    const int tid  = threadIdx.x;
    if (flat < 2560) {
        int i = flat * 256 + tid;
        const float4 v = *(const float4*)&x[4 * i];
        xb[4 * i + 0] = f2bf(v.x);
        xb[4 * i + 1] = f2bf(v.y);
        xb[4 * i + 2] = f2bf(v.z);
        xb[4 * i + 3] = f2bf(v.w);
        return;
    }
    const int wf = flat - 2560;
    const float* src;
    __bf16* dstb;
    int idx, tiles_x, N;
    if (wf < 400)      { src = Wq; dstb = WqkvT;             idx = wf;       tiles_x = 20; N = 640; }
    else if (wf < 500) { src = Wk; dstb = WqkvT + 640 * 640; idx = wf - 400; tiles_x = 5;  N = 160; }
    else if (wf < 600) { src = Wv; dstb = WqkvT + 800 * 640; idx = wf - 500; tiles_x = 5;  N = 160; }
    else               { src = Wo; dstb = WoT;               idx = wf - 600; tiles_x = 20; N = 640; }
    const int n0 = (idx % tiles_x) * 32;
    const int k0 = (idx / tiles_x) * 32;

    __shared__ float t[32][33];
    const int tx = tid & 31, ty = tid >> 5;     // 32 x 8
    #pragma unroll
    for (int i = 0; i < 4; ++i) {
        int r = ty + 8 * i;
        t[r][tx] = src[(size_t)(k0 + r) * N + n0 + tx];
    }
    __syncthreads();
    #pragma unroll
    for (int i = 0; i < 4; ++i) {
        int r = ty + 8 * i;
        dstb[(size_t)(n0 + r) * 640 + k0 + tx] = f2bf(t[tx][r]);
    }
}

// ---------------------------------------------------------------------------
// MFMA bf16 GEMM (r7-proven form): 512 threads = 8 waves (2M x 4N), tile
// 128x128, BK=32, dbuf LDS, single-step-ahead reg prefetch, 1 barrier/step.
// ---------------------------------------------------------------------------
template <typename OutT>
__global__ __launch_bounds__(512) void gemm_bf16_mfma(
    const __bf16* __restrict__ A, const __bf16* __restrict__ BT,
    OutT* __restrict__ C, int M, int N, int K, int ldc)
{
    __shared__ __bf16 As[2][128][40];
    __shared__ __bf16 Bs[2][128][40];
    const int BUFE = 128 * 40;

    const int tid  = threadIdx.x;
    const int wave = tid >> 6;
    const int lane = tid & 63;
    const int wr = wave >> 2, wc = wave & 3;
    const int l15 = lane & 15, lq = lane >> 4;
    const int m0 = blockIdx.y * 128, n0 = blockIdx.x * 128;

    f32x4 acc[4][2];
    #pragma unroll
    for (int m = 0; m < 4; ++m)
        #pragma unroll
        for (int n = 0; n < 2; ++n) acc[m][n] = (f32x4)0.0f;

    const int sArr  = tid >> 8;
    const int sc    = tid & 255;
    const int srow  = sc >> 1;
    const int shalf = sc & 1;
    const __bf16* gsrc = sArr ? BT : A;
    const int     grow = sArr ? n0 : m0;
    const size_t  g0   = (size_t)(grow + srow) * K + 16 * shalf;
    __bf16* ldst = (sArr ? &Bs[0][0][0] : &As[0][0][0]) + srow * 40 + 16 * shalf;

    bf16x8 rg0 = *(const bf16x8*)&gsrc[g0];
    bf16x8 rg1 = *(const bf16x8*)&gsrc[g0 + 8];
    *(bf16x8*)ldst       = rg0;
    *(bf16x8*)(ldst + 8) = rg1;
    __syncthreads();

    const int nk = K >> 5;
    for (int ks = 0; ks < nk; ++ks) {
        const int cur = ks & 1;
        if (ks + 1 < nk) {
            rg0 = *(const bf16x8*)&gsrc[g0 + (size_t)(ks + 1) * 32];
            rg1 = *(const bf16x8*)&gsrc[g0 + (size_t)(ks + 1) * 32 + 8];
        }

        bf16x8 af[4], bfr[2];
        #pragma unroll
        for (int m = 0; m < 4; ++m)
            af[m] = *(const bf16x8*)&As[cur][wr * 64 + m * 16 + l15][8 * lq];
        #pragma unroll
        for (int n = 0; n < 2; ++n)
            bfr[n] = *(const bf16x8*)&Bs[cur][wc * 32 + n * 16 + l15][8 * lq];

        __builtin_amdgcn_s_setprio(1);
        #pragma unroll
        for (int m = 0; m < 4; ++m)
            #pragma unroll
            for (int n = 0; n < 2; ++n)
                acc[m][n] = __builtin_amdgcn_mfma_f32_16x16x32_bf16(af[m], bfr[n], acc[m][n], 0, 0, 0);
        __builtin_amdgcn_s_setprio(0);

        if (ks + 1 < nk) {
            *(bf16x8*)(ldst + (cur ^ 1) * BUFE)     = rg0;
            *(bf16x8*)(ldst + (cur ^ 1) * BUFE + 8) = rg1;
        }
        __syncthreads();
    }

    #pragma unroll
    for (int m = 0; m < 4; ++m) {
        #pragma unroll
        for (int n = 0; n < 2; ++n) {
            const int col = n0 + wc * 32 + n * 16 + l15;
            if (col < N) {
                const int rbase = m0 + wr * 64 + m * 16 + 4 * lq;
                #pragma unroll
                for (int r = 0; r < 4; ++r) {
                    if constexpr (sizeof(OutT) == 2)
                        C[(size_t)(rbase + r) * ldc + col] = f2bf(acc[m][n][r]);
                    else
                        C[(size_t)(rbase + r) * ldc + col] = acc[m][n][r];
                }
            }
        }
    }
}

// ---------------------------------------------------------------------------
// RMSNorm + RoPE: one block per row, 10 heads looped (r8-proven).
// ---------------------------------------------------------------------------
__global__ __launch_bounds__(128) void norm_rope_kernel(
    const unsigned short* __restrict__ qkvb, const float* __restrict__ cosb,
    const float* __restrict__ sinb, const float* __restrict__ qw,
    const float* __restrict__ kw, __bf16* __restrict__ qb,
    __bf16* __restrict__ kb)
{
    const int row = blockIdx.x;
    const int tid = threadIdx.x;
    __shared__ float red[2];

    float c = 0.f, s = 0.f, wqv = 0.f, wkv = 0.f;
    if (tid < HDIM) {
        c   = cosb[(size_t)row * (HDIM / 2) + (tid >> 1)];
        s   = sinb[(size_t)row * (HDIM / 2) + (tid >> 1)];
        wqv = qw[tid];
        wkv = kw[tid];
    }
    const float sgn = (tid & 1) ? 1.0f : -1.0f;
    const float QSCALE = 0.11180339887498948f * 1.4426950408889634f;

    for (int hh = 0; hh < 10; ++hh) {
        const unsigned short* p = (hh < NH)
            ? qkvb + (size_t)row * 960 + hh * HDIM
            : qkvb + (size_t)row * 960 + HIDDEN + (hh - NH) * HDIM;
        float v = (tid < HDIM) ? bf2f(p[tid]) : 0.0f;
        float sq = v * v;
        #pragma unroll
        for (int off = 32; off; off >>= 1) sq += __shfl_down(sq, off);
        if ((tid & 63) == 0) red[tid >> 6] = sq;
        __syncthreads();
        float rms = rsqrtf((red[0] + red[1]) * (1.0f / HDIM) + 1e-5f);

        float w  = (hh < NH) ? wqv : wkv;
        float vn = v * rms * w;
        float vp = __shfl_xor(vn, 1);
        float o  = vn * c + sgn * vp * s;

        if (tid < HDIM) {
            if (hh < NH) qb[(size_t)row * HIDDEN + hh * HDIM + tid] = (__bf16)(o * QSCALE);
            else         kb[(size_t)row * (NKV * HDIM) + (hh - NH) * HDIM + tid] = (__bf16)o;
        }
        __syncthreads();
    }
}

// ---------------------------------------------------------------------------
// V transpose: vtb[kvh][d][seq] = panel v cols (bf16 bit copy).
// ---------------------------------------------------------------------------
__global__ __launch_bounds__(256) void v_transpose(
    const unsigned short* __restrict__ qkvb, unsigned short* __restrict__ vtb)
{
    __shared__ unsigned short t[32][33];
    const int s0 = blockIdx.x * 32;
    const int c0 = blockIdx.y * 32;
    const int tx = threadIdx.x, ty = threadIdx.y;
    #pragma unroll
    for (int i = 0; i < 4; ++i)
        t[ty + 8 * i][tx] = qkvb[(size_t)(s0 + ty + 8 * i) * 960 + 800 + c0 + tx];
    __syncthreads();
    #pragma unroll
    for (int i = 0; i < 4; ++i) {
        int g = c0 + ty + 8 * i;           // 0..159
        int kvh = g / HDIM, d = g % HDIM;
        vtb[((size_t)kvh * HDIM + d) * SEQ + s0 + tx] = t[tx][ty + 8 * i];
    }
}

// ---------------------------------------------------------------------------
// MFMA flash attention v5: BQ=32, 128 threads = 2 waves, 1024 blocks ->
// 4 blocks/CU (phase-diverse). Single-buffered Ks/Vt (29.4 KB), 2 barriers
// per tile, single-tile-ahead reg prefetch (r8-proven schedule), exp2-domain
// softmax with exact skip-rescale. qb pre-scaled by scale*log2e. Output bf16.
// Schedule: [load t+1] S -> bar1 -> write K(t+1) -> softmax -> PV -> bar2
//           -> write V(t+1).
// ---------------------------------------------------------------------------
__global__ __launch_bounds__(128) void flash_attn_mfma(
    const __bf16* __restrict__ qb, const __bf16* __restrict__ kb,
    const __bf16* __restrict__ vtb, __bf16* __restrict__ attnb)
{
    const int i0   = blockIdx.x * BQ;
    const int h    = blockIdx.y;
    const int kvh  = h >> 2;
    const int tid  = threadIdx.x;        // 0..127
    const int w    = tid >> 6;           // 0..1
    const int lane = tid & 63;
    const int l15  = lane & 15;
    const int lq   = lane >> 4;

    __shared__ __bf16 Ks[BK][KSTR];      // 13312 B
    __shared__ __bf16 Vt[HDIM][VSTR];    // 11520 B
    __shared__ __bf16 Pl[BQ][VSTR];      //  4608 B   (29440 B -> 4 blk/CU by grid)

    // zero K pad columns 80..95 (all 128 threads: 64 rows x 2 chunks)
    {
        int r = tid >> 1, c = HDIM + 8 * (tid & 1);
        *(float4*)&Ks[r][c] = make_float4(0.f, 0.f, 0.f, 0.f);
    }

    // staging: 640 chunks of 8 bf16, exactly 5 per thread
    int koff[5], voff[5];
    __bf16* ksdst[5];
    __bf16* vsdst[5];
    #pragma unroll
    for (int i = 0; i < 5; ++i) {
        int c = tid + 128 * i;
        koff[i] = (c / 10) * (NKV * HDIM) + 8 * (c % 10);
        voff[i] = (c >> 3) * SEQ + 8 * (c & 7);
        ksdst[i] = &Ks[c / 10][8 * (c % 10)];
        vsdst[i] = &Vt[c >> 3][8 * (c & 7)];
    }
    const __bf16* kbase = kb + kvh * HDIM;
    const __bf16* vbase = vtb + (size_t)kvh * HDIM * SEQ;

    // preload Q A-fragments (wave rows i0 + 16w + l15)
    bf16x8 qf[3];
    {
        const __bf16* qrow = qb + (size_t)(i0 + 16 * w + l15) * HIDDEN + h * HDIM;
        #pragma unroll
        for (int ks = 0; ks < 3; ++ks) {
            int off = 32 * ks + 8 * lq;
            if (off >= HDIM) off = 0;     // dummy: multiplied by zeroed K pad
            qf[ks] = *(const bf16x8*)&qrow[off];
        }
    }

    float m_i[4], l_i[4];
    f32x4 o[5];
    #pragma unroll
    for (int r = 0; r < 4; ++r) { m_i[r] = -1e30f; l_i[r] = 0.0f; }
    #pragma unroll
    for (int n = 0; n < 5; ++n) o[n] = (f32x4)0.0f;

    const int w_lo   = i0 - (WINDOW - 1);
    const int w_tile = (w_lo <= 0) ? 0 : (w_lo & ~(BK - 1));
    const int n_win  = (i0 - w_tile) / BK + 1;   // covers keys up to >= i0+BQ-1
    const int n_tiles = n_win + ((w_tile > 0) ? 1 : 0);

    // prologue: stage tile 0
    bf16x8 krg[5], vrg[5];
    #pragma unroll
    for (int i = 0; i < 5; ++i) {
        krg[i] = *(const bf16x8*)&kbase[(size_t)w_tile * (NKV * HDIM) + koff[i]];
        vrg[i] = *(const bf16x8*)&vbase[(size_t)w_tile + voff[i]];
    }
    #pragma unroll
    for (int i = 0; i < 5; ++i) {
        *(bf16x8*)ksdst[i] = krg[i];
        *(bf16x8*)vsdst[i] = vrg[i];
    }
    __syncthreads();

    for (int t = 0; t < n_tiles; ++t) {
        const int j0 = (t < n_win) ? (w_tile + t * BK) : 0;
        const bool more = (t + 1 < n_tiles);

        // ---- prefetch next tile into registers ----
        if (more) {
            const int j1 = (t + 1 < n_win) ? (w_tile + (t + 1) * BK) : 0;
            #pragma unroll
            for (int i = 0; i < 5; ++i) {
                krg[i] = *(const bf16x8*)&kbase[(size_t)j1 * (NKV * HDIM) + koff[i]];
                vrg[i] = *(const bf16x8*)&vbase[(size_t)j1 + voff[i]];
            }
        }

        // ---- S = Q K^T : 12 MFMA ----
        f32x4 sacc[4];
        #pragma unroll
        for (int n = 0; n < 4; ++n) sacc[n] = (f32x4)0.0f;
        __builtin_amdgcn_s_setprio(1);
        #pragma unroll
        for (int ks = 0; ks < 3; ++ks) {
            #pragma unroll
            for (int n = 0; n < 4; ++n) {
                bf16x8 kf = *(const bf16x8*)&Ks[n * 16 + l15][32 * ks + 8 * lq];
                sacc[n] = __builtin_amdgcn_mfma_f32_16x16x32_bf16(qf[ks], kf, sacc[n], 0, 0, 0);
            }
        }
        __builtin_amdgcn_s_setprio(0);

        __syncthreads();                    // bar1: S reads of Ks done
        if (more) {
            #pragma unroll
            for (int i = 0; i < 5; ++i) *(bf16x8*)ksdst[i] = krg[i];
        }

        // ---- mask ----
        const bool full = (j0 >= i0 - 480) && (j0 <= i0 - 64);
        if (!full) {
            #pragma unroll
            for (int n = 0; n < 4; ++n) {
                int j = j0 + 16 * n + l15;
                #pragma unroll
                for (int r = 0; r < 4; ++r) {
                    int i = i0 + 16 * w + 4 * lq + r;
                    bool allowed = (j <= i) && ((j >= i - (WINDOW - 1)) || (j < SINK));
                    if (!allowed) sacc[n][r] = -1e30f;
                }
            }
        }

        // ---- online softmax (exp2 domain, exact skip-rescale) ----
        #pragma unroll
        for (int r = 0; r < 4; ++r) {
            float rmax = fmaxf(fmaxf(sacc[0][r], sacc[1][r]), fmaxf(sacc[2][r], sacc[3][r]));
            rmax = fmaxf(rmax, __shfl_xor(rmax, 1));
            rmax = fmaxf(rmax, __shfl_xor(rmax, 2));
            rmax = fmaxf(rmax, __shfl_xor(rmax, 4));
            rmax = fmaxf(rmax, __shfl_xor(rmax, 8));
            if (rmax > m_i[r]) {
                float alpha = fexp2(m_i[r] - rmax);
                m_i[r] = rmax;
                l_i[r] *= alpha;
                #pragma unroll
                for (int n = 0; n < 5; ++n) o[n][r] *= alpha;
            }
            float rsum = 0.0f;
            #pragma unroll
            for (int n = 0; n < 4; ++n) {
                float pe = fexp2(sacc[n][r] - m_i[r]);
                Pl[16 * w + 4 * lq + r][16 * n + l15] = (__bf16)pe;
                rsum += pe;
            }
            rsum += __shfl_xor(rsum, 1);
            rsum += __shfl_xor(rsum, 2);
            rsum += __shfl_xor(rsum, 4);
            rsum += __shfl_xor(rsum, 8);
            l_i[r] += rsum;
        }

        // ---- O += P V : wave-private P rows, 10 MFMA ----
        __builtin_amdgcn_s_setprio(1);
        #pragma unroll
        for (int ks = 0; ks < 2; ++ks) {
            bf16x8 pf = *(const bf16x8*)&Pl[16 * w + l15][32 * ks + 8 * lq];
            #pragma unroll
            for (int n = 0; n < 5; ++n) {
                bf16x8 vf = *(const bf16x8*)&Vt[16 * n + l15][32 * ks + 8 * lq];
                o[n] = __builtin_amdgcn_mfma_f32_16x16x32_bf16(pf, vf, o[n], 0, 0, 0);
            }
        }
        __builtin_amdgcn_s_setprio(0);

        __syncthreads();                    // bar2: PV reads of Vt done
        if (more) {
            #pragma unroll
            for (int i = 0; i < 5; ++i) *(bf16x8*)vsdst[i] = vrg[i];
        }
    }

    // ---- epilogue ----
    #pragma unroll
    for (int r = 0; r < 4; ++r) {
        float inv = 1.0f / l_i[r];
        int row = i0 + 16 * w + 4 * lq + r;
        #pragma unroll
        for (int n = 0; n < 5; ++n)
            attnb[(size_t)row * HIDDEN + h * HDIM + 16 * n + l15] = (__bf16)(o[n][r] * inv);
    }
}

// ---------------------------------------------------------------------------
extern "C" void kernel_launch(void* const* d_in, const int* in_sizes, int n_in,
                              void* d_out, int out_size, void* d_ws, size_t ws_size,
                              hipStream_t stream)
{
    const float* x    = (const float*)d_in[0];
    const float* cosb = (const float*)d_in[1];
    const float* sinb = (const float*)d_in[2];
    const float* Wq   = (const float*)d_in[3];
    const float* Wk   = (const float*)d_in[4];
    const float* Wv   = (const float*)d_in[5];
    const float* Wo   = (const float*)d_in[6];
    const float* qw   = (const float*)d_in[7];
    const float* kw   = (const float*)d_in[8];
    float* out = (float*)d_out;

    char* ws = (char*)d_ws;
    __bf16* qkvb  = (__bf16*)ws;                                 // [4096][960]
    __bf16* xb    = qkvb + (size_t)SEQ * 960;                    // [4096][640] -> attnb
    __bf16* qb    = xb   + (size_t)SEQ * HIDDEN;                 // [4096][640]
    __bf16* kb    = qb   + (size_t)SEQ * HIDDEN;                 // [4096][160]
    __bf16* vtb   = kb   + (size_t)SEQ * 160;                    // [2][80][4096]
    __bf16* WqkvT = vtb  + (size_t)2 * HDIM * SEQ;               // [1024][640]
    __bf16* WoT   = WqkvT + (size_t)1024 * HIDDEN;               // [640][640]

    prep_kernel<<<dim3(3560), dim3(256), 0, stream>>>(
        x, Wq, Wk, Wv, Wo, xb, WqkvT, WoT);

    gemm_bf16_mfma<__bf16><<<dim3(8, SEQ / 128), dim3(512), 0, stream>>>(
        xb, WqkvT, qkvb, SEQ, 960, HIDDEN, 960);

    norm_rope_kernel<<<dim3(SEQ), dim3(128), 0, stream>>>(
        (const unsigned short*)qkvb, cosb, sinb, qw, kw, qb, kb);

    v_transpose<<<dim3(SEQ / 32, 160 / 32), dim3(32, 8), 0, stream>>>(
        (const unsigned short*)qkvb, (unsigned short*)vtb);

    flash_attn_mfma<<<dim3(SEQ / BQ, NH), dim3(128), 0, stream>>>(
        qb, kb, vtb, xb);

    gemm_bf16_mfma<float><<<dim3(HIDDEN / 128, SEQ / 128), dim3(512), 0, stream>>>(
        xb, WoT, out, SEQ, HIDDEN, HIDDEN, HIDDEN);
}

// Round 11
// 81.251 us; speedup vs baseline: 1.3054x; 1.0994x over previous
//
#include <hip/hip_runtime.h>
#include <hip/hip_bf16.h>
#include <stdint.h>

#define SEQ     4096
#define HIDDEN  640
#define HDIM    80
#define NH      8
#define NKV     2
#define WINDOW  512
#define SINK    4
#define BQG     32    // flash q-tile (shared by 4 heads)
#define BK      64
#define KSTR    104   // Ks row stride (bf16): 2-way banks on b128 reads
#define VSTR    72    // Vt/Pl row stride (bf16): 2-way banks

typedef __bf16 bf16x8 __attribute__((ext_vector_type(8)));
typedef float  f32x4  __attribute__((ext_vector_type(4)));

__device__ inline __bf16 f2bf(float f) {
    union { float f; uint32_t u; } x; x.f = f;
    uint32_t r = x.u + 0x7FFF + ((x.u >> 16) & 1);   // RNE, no NaN inputs
    union { unsigned short s; __bf16 b; } y; y.s = (unsigned short)(r >> 16);
    return y.b;
}
__device__ inline float bf2f(unsigned short u) {
    union { uint32_t u; float f; } c; c.u = ((uint32_t)u) << 16; return c.f;
}
__device__ inline float fexp2(float x) {
#if __has_builtin(__builtin_amdgcn_exp2f)
    return __builtin_amdgcn_exp2f(x);
#else
    return exp2f(x);
#endif
}

// ---------------------------------------------------------------------------
// Fused prep: x -> bf16 (blocks [0,2560)) + all weight transposes
// (blocks [2560,3560), 32x32 tiles).
// ---------------------------------------------------------------------------
__global__ __launch_bounds__(256) void prep_kernel(
    const float* __restrict__ x, const float* __restrict__ Wq,
    const float* __restrict__ Wk, const float* __restrict__ Wv,
    const float* __restrict__ Wo, __bf16* __restrict__ xb,
    __bf16* __restrict__ WqkvT, __bf16* __restrict__ WoT)
{
    const int flat = blockIdx.x;
    const int tid  = threadIdx.x;
    if (flat < 2560) {
        int i = flat * 256 + tid;
        const float4 v = *(const float4*)&x[4 * i];
        xb[4 * i + 0] = f2bf(v.x);
        xb[4 * i + 1] = f2bf(v.y);
        xb[4 * i + 2] = f2bf(v.z);
        xb[4 * i + 3] = f2bf(v.w);
        return;
    }
    const int wf = flat - 2560;
    const float* src;
    __bf16* dstb;
    int idx, tiles_x, N;
    if (wf < 400)      { src = Wq; dstb = WqkvT;             idx = wf;       tiles_x = 20; N = 640; }
    else if (wf < 500) { src = Wk; dstb = WqkvT + 640 * 640; idx = wf - 400; tiles_x = 5;  N = 160; }
    else if (wf < 600) { src = Wv; dstb = WqkvT + 800 * 640; idx = wf - 500; tiles_x = 5;  N = 160; }
    else               { src = Wo; dstb = WoT;               idx = wf - 600; tiles_x = 20; N = 640; }
    const int n0 = (idx % tiles_x) * 32;
    const int k0 = (idx / tiles_x) * 32;

    __shared__ float t[32][33];
    const int tx = tid & 31, ty = tid >> 5;     // 32 x 8
    #pragma unroll
    for (int i = 0; i < 4; ++i) {
        int r = ty + 8 * i;
        t[r][tx] = src[(size_t)(k0 + r) * N + n0 + tx];
    }
    __syncthreads();
    #pragma unroll
    for (int i = 0; i < 4; ++i) {
        int r = ty + 8 * i;
        dstb[(size_t)(n0 + r) * 640 + k0 + tx] = f2bf(t[tx][r]);
    }
}

// ---------------------------------------------------------------------------
// MFMA bf16 GEMM (r7-proven): 512 threads = 8 waves (2M x 4N), tile 128x128,
// BK=32, dbuf LDS, single-step-ahead reg prefetch, 1 barrier/step.
// ---------------------------------------------------------------------------
template <typename OutT>
__global__ __launch_bounds__(512) void gemm_bf16_mfma(
    const __bf16* __restrict__ A, const __bf16* __restrict__ BT,
    OutT* __restrict__ C, int M, int N, int K, int ldc)
{
    __shared__ __bf16 As[2][128][40];
    __shared__ __bf16 Bs[2][128][40];
    const int BUFE = 128 * 40;

    const int tid  = threadIdx.x;
    const int wave = tid >> 6;
    const int lane = tid & 63;
    const int wr = wave >> 2, wc = wave & 3;
    const int l15 = lane & 15, lq = lane >> 4;
    const int m0 = blockIdx.y * 128, n0 = blockIdx.x * 128;

    f32x4 acc[4][2];
    #pragma unroll
    for (int m = 0; m < 4; ++m)
        #pragma unroll
        for (int n = 0; n < 2; ++n) acc[m][n] = (f32x4)0.0f;

    const int sArr  = tid >> 8;
    const int sc    = tid & 255;
    const int srow  = sc >> 1;
    const int shalf = sc & 1;
    const __bf16* gsrc = sArr ? BT : A;
    const int     grow = sArr ? n0 : m0;
    const size_t  g0   = (size_t)(grow + srow) * K + 16 * shalf;
    __bf16* ldst = (sArr ? &Bs[0][0][0] : &As[0][0][0]) + srow * 40 + 16 * shalf;

    bf16x8 rg0 = *(const bf16x8*)&gsrc[g0];
    bf16x8 rg1 = *(const bf16x8*)&gsrc[g0 + 8];
    *(bf16x8*)ldst       = rg0;
    *(bf16x8*)(ldst + 8) = rg1;
    __syncthreads();

    const int nk = K >> 5;
    for (int ks = 0; ks < nk; ++ks) {
        const int cur = ks & 1;
        if (ks + 1 < nk) {
            rg0 = *(const bf16x8*)&gsrc[g0 + (size_t)(ks + 1) * 32];
            rg1 = *(const bf16x8*)&gsrc[g0 + (size_t)(ks + 1) * 32 + 8];
        }

        bf16x8 af[4], bfr[2];
        #pragma unroll
        for (int m = 0; m < 4; ++m)
            af[m] = *(const bf16x8*)&As[cur][wr * 64 + m * 16 + l15][8 * lq];
        #pragma unroll
        for (int n = 0; n < 2; ++n)
            bfr[n] = *(const bf16x8*)&Bs[cur][wc * 32 + n * 16 + l15][8 * lq];

        __builtin_amdgcn_s_setprio(1);
        #pragma unroll
        for (int m = 0; m < 4; ++m)
            #pragma unroll
            for (int n = 0; n < 2; ++n)
                acc[m][n] = __builtin_amdgcn_mfma_f32_16x16x32_bf16(af[m], bfr[n], acc[m][n], 0, 0, 0);
        __builtin_amdgcn_s_setprio(0);

        if (ks + 1 < nk) {
            *(bf16x8*)(ldst + (cur ^ 1) * BUFE)     = rg0;
            *(bf16x8*)(ldst + (cur ^ 1) * BUFE + 8) = rg1;
        }
        __syncthreads();
    }

    #pragma unroll
    for (int m = 0; m < 4; ++m) {
        #pragma unroll
        for (int n = 0; n < 2; ++n) {
            const int col = n0 + wc * 32 + n * 16 + l15;
            if (col < N) {
                const int rbase = m0 + wr * 64 + m * 16 + 4 * lq;
                #pragma unroll
                for (int r = 0; r < 4; ++r) {
                    if constexpr (sizeof(OutT) == 2)
                        C[(size_t)(rbase + r) * ldc + col] = f2bf(acc[m][n][r]);
                    else
                        C[(size_t)(rbase + r) * ldc + col] = acc[m][n][r];
                }
            }
        }
    }
}

// ---------------------------------------------------------------------------
// Fused RMSNorm+RoPE (blocks [0,2048): 2 rows each) and V-transpose
// (blocks [2048,2688): 32x32 tiles). 256 threads.
// ---------------------------------------------------------------------------
__global__ __launch_bounds__(256) void normrope_vt_kernel(
    const unsigned short* __restrict__ qkvb, const float* __restrict__ cosb,
    const float* __restrict__ sinb, const float* __restrict__ qw,
    const float* __restrict__ kw, __bf16* __restrict__ qb,
    __bf16* __restrict__ kb, unsigned short* __restrict__ vtb)
{
    const int flat = blockIdx.x;
    const int tid  = threadIdx.x;

    __shared__ float red[4];
    __shared__ unsigned short t[32][33];

    if (flat < 2048) {
        const int half = tid >> 7;           // 0..1 -> row pair
        const int lt   = tid & 127;
        const int row  = flat * 2 + half;

        float c = 0.f, s = 0.f, wqv = 0.f, wkv = 0.f;
        if (lt < HDIM) {
            c   = cosb[(size_t)row * (HDIM / 2) + (lt >> 1)];
            s   = sinb[(size_t)row * (HDIM / 2) + (lt >> 1)];
            wqv = qw[lt];
            wkv = kw[lt];
        }
        const float sgn = (lt & 1) ? 1.0f : -1.0f;
        const float QSCALE = 0.11180339887498948f * 1.4426950408889634f;

        for (int hh = 0; hh < 10; ++hh) {
            const unsigned short* p = (hh < NH)
                ? qkvb + (size_t)row * 960 + hh * HDIM
                : qkvb + (size_t)row * 960 + HIDDEN + (hh - NH) * HDIM;
            float v = (lt < HDIM) ? bf2f(p[lt]) : 0.0f;
            float sq = v * v;
            #pragma unroll
            for (int off = 32; off; off >>= 1) sq += __shfl_down(sq, off);
            if ((lt & 63) == 0) red[half * 2 + (lt >> 6)] = sq;
            __syncthreads();
            float rms = rsqrtf((red[half * 2] + red[half * 2 + 1]) * (1.0f / HDIM) + 1e-5f);

            float w  = (hh < NH) ? wqv : wkv;
            float vn = v * rms * w;
            float vp = __shfl_xor(vn, 1);
            float o  = vn * c + sgn * vp * s;

            if (lt < HDIM) {
                if (hh < NH) qb[(size_t)row * HIDDEN + hh * HDIM + lt] = (__bf16)(o * QSCALE);
                else         kb[(size_t)row * (NKV * HDIM) + (hh - NH) * HDIM + lt] = (__bf16)o;
            }
            __syncthreads();
        }
        return;
    }

    // ---- V transpose: vtb[kvh][d][seq] ----
    const int idx = flat - 2048;             // 0..639
    const int s0 = (idx & 127) * 32;
    const int c0 = (idx >> 7) * 32;
    const int tx = tid & 31, ty = tid >> 5;  // 32 x 8
    #pragma unroll
    for (int i = 0; i < 4; ++i)
        t[ty + 8 * i][tx] = qkvb[(size_t)(s0 + ty + 8 * i) * 960 + 800 + c0 + tx];
    __syncthreads();
    #pragma unroll
    for (int i = 0; i < 4; ++i) {
        int g = c0 + ty + 8 * i;             // 0..159
        int kvh = g / HDIM, d = g % HDIM;
        vtb[((size_t)kvh * HDIM + d) * SEQ + s0 + tx] = t[tx][ty + 8 * i];
    }
}

// ---------------------------------------------------------------------------
// GQA-fused MFMA flash attention: block = (32-query tile, kvh), 512 threads
// = 8 waves = 4 q-heads x 2 waves x 16 rows. ONE K/V stage serves 4 heads:
// 176 MFMA per tile between 2 barriers. Grid (128, 2) = 256 blocks (1/CU).
// Single-buffered Ks/Vt/Pl (43.3 KB), single-tile-ahead reg prefetch,
// exp2-domain softmax with exact skip-rescale. qb pre-scaled by scale*log2e.
// Schedule: [load t+1] S -> bar1 -> write K(t+1) -> softmax -> PV -> bar2
//           -> write V(t+1).
// ---------------------------------------------------------------------------
__global__ __launch_bounds__(512) void flash_attn_mfma(
    const __bf16* __restrict__ qb, const __bf16* __restrict__ kb,
    const __bf16* __restrict__ vtb, __bf16* __restrict__ attnb)
{
    const int i0   = blockIdx.x * BQG;
    const int kvh  = blockIdx.y;
    const int tid  = threadIdx.x;        // 0..511
    const int w    = tid >> 6;           // 0..7
    const int h    = kvh * 4 + (w >> 1); // q-head of this wave
    const int wsub = w & 1;              // 16-row half of the q-tile
    const int lane = tid & 63;
    const int l15  = lane & 15;
    const int lq   = lane >> 4;

    __shared__ __bf16 Ks[BK][KSTR];      // 13312 B
    __shared__ __bf16 Vt[HDIM][VSTR];    // 11520 B
    __shared__ __bf16 Pl[128][VSTR];     // 18432 B  (total 43264 B)

    // zero K pad columns 80..95 (64 rows x 2 chunks)
    if (tid < 128) {
        int r = tid >> 1, c = HDIM + 8 * (tid & 1);
        *(float4*)&Ks[r][c] = make_float4(0.f, 0.f, 0.f, 0.f);
    }

    // staging: 640 chunks of 8 bf16 each for K and V; thread covers
    // chunk tid (all) and tid+512 (tid<128 only).
    int koff[2], voff[2];
    __bf16* ksdst[2];
    __bf16* vsdst[2];
    bool act[2];
    #pragma unroll
    for (int i = 0; i < 2; ++i) {
        int c = tid + 512 * i;
        act[i] = (c < 640);
        int cc = act[i] ? c : 0;
        koff[i] = (cc / 10) * (NKV * HDIM) + 8 * (cc % 10);
        voff[i] = (cc >> 3) * SEQ + 8 * (cc & 7);
        ksdst[i] = &Ks[cc / 10][8 * (cc % 10)];
        vsdst[i] = &Vt[cc >> 3][8 * (cc & 7)];
    }
    const __bf16* kbase = kb + kvh * HDIM;
    const __bf16* vbase = vtb + (size_t)kvh * HDIM * SEQ;

    // preload Q A-fragments (wave rows i0 + 16*wsub + l15, head h)
    bf16x8 qf[3];
    {
        const __bf16* qrow = qb + (size_t)(i0 + 16 * wsub + l15) * HIDDEN + h * HDIM;
        #pragma unroll
        for (int ks = 0; ks < 3; ++ks) {
            int off = 32 * ks + 8 * lq;
            if (off >= HDIM) off = 0;     // dummy: multiplied by zeroed K pad
            qf[ks] = *(const bf16x8*)&qrow[off];
        }
    }

    float m_i[4], l_i[4];
    f32x4 o[5];
    #pragma unroll
    for (int r = 0; r < 4; ++r) { m_i[r] = -1e30f; l_i[r] = 0.0f; }
    #pragma unroll
    for (int n = 0; n < 5; ++n) o[n] = (f32x4)0.0f;

    const int w_lo   = i0 - (WINDOW - 1);
    const int w_tile = (w_lo <= 0) ? 0 : (w_lo & ~(BK - 1));
    const int n_win  = (i0 - w_tile) / BK + 1;
    const int n_tiles = n_win + ((w_tile > 0) ? 1 : 0);

    // prologue: stage tile 0
    bf16x8 krg[2], vrg[2];
    #pragma unroll
    for (int i = 0; i < 2; ++i) {
        if (act[i]) {
            krg[i] = *(const bf16x8*)&kbase[(size_t)w_tile * (NKV * HDIM) + koff[i]];
            vrg[i] = *(const bf16x8*)&vbase[(size_t)w_tile + voff[i]];
        }
    }
    #pragma unroll
    for (int i = 0; i < 2; ++i) {
        if (act[i]) {
            *(bf16x8*)ksdst[i] = krg[i];
            *(bf16x8*)vsdst[i] = vrg[i];
        }
    }
    __syncthreads();

    for (int t = 0; t < n_tiles; ++t) {
        const int j0 = (t < n_win) ? (w_tile + t * BK) : 0;
        const bool more = (t + 1 < n_tiles);

        // ---- prefetch next tile into registers ----
        if (more) {
            const int j1 = (t + 1 < n_win) ? (w_tile + (t + 1) * BK) : 0;
            #pragma unroll
            for (int i = 0; i < 2; ++i) {
                if (act[i]) {
                    krg[i] = *(const bf16x8*)&kbase[(size_t)j1 * (NKV * HDIM) + koff[i]];
                    vrg[i] = *(const bf16x8*)&vbase[(size_t)j1 + voff[i]];
                }
            }
        }

        // ---- S = Q K^T : 12 MFMA per wave ----
        f32x4 sacc[4];
        #pragma unroll
        for (int n = 0; n < 4; ++n) sacc[n] = (f32x4)0.0f;
        __builtin_amdgcn_s_setprio(1);
        #pragma unroll
        for (int ks = 0; ks < 3; ++ks) {
            #pragma unroll
            for (int n = 0; n < 4; ++n) {
                bf16x8 kf = *(const bf16x8*)&Ks[n * 16 + l15][32 * ks + 8 * lq];
                sacc[n] = __builtin_amdgcn_mfma_f32_16x16x32_bf16(qf[ks], kf, sacc[n], 0, 0, 0);
            }
        }
        __builtin_amdgcn_s_setprio(0);

        __syncthreads();                    // bar1: S reads of Ks done
        if (more) {
            #pragma unroll
            for (int i = 0; i < 2; ++i)
                if (act[i]) *(bf16x8*)ksdst[i] = krg[i];
        }

        // ---- mask (full-tile test for 32-row q-tiles) ----
        const bool full = (j0 >= i0 - 480) && (j0 <= i0 - 64);
        if (!full) {
            #pragma unroll
            for (int n = 0; n < 4; ++n) {
                int j = j0 + 16 * n + l15;
                #pragma unroll
                for (int r = 0; r < 4; ++r) {
                    int i = i0 + 16 * wsub + 4 * lq + r;
                    bool allowed = (j <= i) && ((j >= i - (WINDOW - 1)) || (j < SINK));
                    if (!allowed) sacc[n][r] = -1e30f;
                }
            }
        }

        // ---- online softmax (exp2 domain, exact skip-rescale) ----
        #pragma unroll
        for (int r = 0; r < 4; ++r) {
            float rmax = fmaxf(fmaxf(sacc[0][r], sacc[1][r]), fmaxf(sacc[2][r], sacc[3][r]));
            rmax = fmaxf(rmax, __shfl_xor(rmax, 1));
            rmax = fmaxf(rmax, __shfl_xor(rmax, 2));
            rmax = fmaxf(rmax, __shfl_xor(rmax, 4));
            rmax = fmaxf(rmax, __shfl_xor(rmax, 8));
            if (rmax > m_i[r]) {
                float alpha = fexp2(m_i[r] - rmax);
                m_i[r] = rmax;
                l_i[r] *= alpha;
                #pragma unroll
                for (int n = 0; n < 5; ++n) o[n][r] *= alpha;
            }
            float rsum = 0.0f;
            #pragma unroll
            for (int n = 0; n < 4; ++n) {
                float pe = fexp2(sacc[n][r] - m_i[r]);
                Pl[16 * w + 4 * lq + r][16 * n + l15] = (__bf16)pe;
                rsum += pe;
            }
            rsum += __shfl_xor(rsum, 1);
            rsum += __shfl_xor(rsum, 2);
            rsum += __shfl_xor(rsum, 4);
            rsum += __shfl_xor(rsum, 8);
            l_i[r] += rsum;
        }

        // ---- O += P V : wave-private P rows, 10 MFMA per wave ----
        __builtin_amdgcn_s_setprio(1);
        #pragma unroll
        for (int ks = 0; ks < 2; ++ks) {
            bf16x8 pf = *(const bf16x8*)&Pl[16 * w + l15][32 * ks + 8 * lq];
            #pragma unroll
            for (int n = 0; n < 5; ++n) {
                bf16x8 vf = *(const bf16x8*)&Vt[16 * n + l15][32 * ks + 8 * lq];
                o[n] = __builtin_amdgcn_mfma_f32_16x16x32_bf16(pf, vf, o[n], 0, 0, 0);
            }
        }
        __builtin_amdgcn_s_setprio(0);

        __syncthreads();                    // bar2: PV reads of Vt done
        if (more) {
            #pragma unroll
            for (int i = 0; i < 2; ++i)
                if (act[i]) *(bf16x8*)vsdst[i] = vrg[i];
        }
    }

    // ---- epilogue ----
    #pragma unroll
    for (int r = 0; r < 4; ++r) {
        float inv = 1.0f / l_i[r];
        int row = i0 + 16 * wsub + 4 * lq + r;
        #pragma unroll
        for (int n = 0; n < 5; ++n)
            attnb[(size_t)row * HIDDEN + h * HDIM + 16 * n + l15] = (__bf16)(o[n][r] * inv);
    }
}

// ---------------------------------------------------------------------------
extern "C" void kernel_launch(void* const* d_in, const int* in_sizes, int n_in,
                              void* d_out, int out_size, void* d_ws, size_t ws_size,
                              hipStream_t stream)
{
    const float* x    = (const float*)d_in[0];
    const float* cosb = (const float*)d_in[1];
    const float* sinb = (const float*)d_in[2];
    const float* Wq   = (const float*)d_in[3];
    const float* Wk   = (const float*)d_in[4];
    const float* Wv   = (const float*)d_in[5];
    const float* Wo   = (const float*)d_in[6];
    const float* qw   = (const float*)d_in[7];
    const float* kw   = (const float*)d_in[8];
    float* out = (float*)d_out;

    char* ws = (char*)d_ws;
    __bf16* qkvb  = (__bf16*)ws;                                 // [4096][960]
    __bf16* xb    = qkvb + (size_t)SEQ * 960;                    // [4096][640] -> attnb
    __bf16* qb    = xb   + (size_t)SEQ * HIDDEN;                 // [4096][640]
    __bf16* kb    = qb   + (size_t)SEQ * HIDDEN;                 // [4096][160]
    __bf16* vtb   = kb   + (size_t)SEQ * 160;                    // [2][80][4096]
    __bf16* WqkvT = vtb  + (size_t)2 * HDIM * SEQ;               // [1024][640]
    __bf16* WoT   = WqkvT + (size_t)1024 * HIDDEN;               // [640][640]

    prep_kernel<<<dim3(3560), dim3(256), 0, stream>>>(
        x, Wq, Wk, Wv, Wo, xb, WqkvT, WoT);

    gemm_bf16_mfma<__bf16><<<dim3(8, SEQ / 128), dim3(512), 0, stream>>>(
        xb, WqkvT, qkvb, SEQ, 960, HIDDEN, 960);

    normrope_vt_kernel<<<dim3(2688), dim3(256), 0, stream>>>(
        (const unsigned short*)qkvb, cosb, sinb, qw, kw, qb, kb,
        (unsigned short*)vtb);

    flash_attn_mfma<<<dim3(SEQ / BQG, NKV), dim3(512), 0, stream>>>(
        qb, kb, vtb, xb);

    gemm_bf16_mfma<float><<<dim3(HIDDEN / 128, SEQ / 128), dim3(512), 0, stream>>>(
        xb, WoT, out, SEQ, HIDDEN, HIDDEN, HIDDEN);
}

// Round 12
// 75.917 us; speedup vs baseline: 1.3971x; 1.0703x over previous
//
#include <hip/hip_runtime.h>
#include <hip/hip_bf16.h>
#include <stdint.h>

#define SEQ     4096
#define HIDDEN  640
#define HDIM    80
#define NH      8
#define NKV     2
#define WINDOW  512
#define SINK    4
#define BQG     32    // flash q-tile (shared by 4 heads)
#define BK      128   // flash key-tile
#define KSTR    104   // Ks row stride (bf16): 2-way banks on b128 reads
#define VSTR    136   // Vt/Pl row stride (bf16): 2-way banks (128+8)

typedef __bf16 bf16x8 __attribute__((ext_vector_type(8)));
typedef float  f32x4  __attribute__((ext_vector_type(4)));

__device__ inline __bf16 f2bf(float f) {
    union { float f; uint32_t u; } x; x.f = f;
    uint32_t r = x.u + 0x7FFF + ((x.u >> 16) & 1);   // RNE, no NaN inputs
    union { unsigned short s; __bf16 b; } y; y.s = (unsigned short)(r >> 16);
    return y.b;
}
__device__ inline float bf2f(unsigned short u) {
    union { uint32_t u; float f; } c; c.u = ((uint32_t)u) << 16; return c.f;
}
__device__ inline float fexp2(float x) {
#if __has_builtin(__builtin_amdgcn_exp2f)
    return __builtin_amdgcn_exp2f(x);
#else
    return exp2f(x);
#endif
}

// ---------------------------------------------------------------------------
// Fused prep: x -> bf16 (blocks [0,2560)) + all weight transposes
// (blocks [2560,3560), 32x32 tiles).
// ---------------------------------------------------------------------------
__global__ __launch_bounds__(256) void prep_kernel(
    const float* __restrict__ x, const float* __restrict__ Wq,
    const float* __restrict__ Wk, const float* __restrict__ Wv,
    const float* __restrict__ Wo, __bf16* __restrict__ xb,
    __bf16* __restrict__ WqkvT, __bf16* __restrict__ WoT)
{
    const int flat = blockIdx.x;
    const int tid  = threadIdx.x;
    if (flat < 2560) {
        int i = flat * 256 + tid;
        const float4 v = *(const float4*)&x[4 * i];
        xb[4 * i + 0] = f2bf(v.x);
        xb[4 * i + 1] = f2bf(v.y);
        xb[4 * i + 2] = f2bf(v.z);
        xb[4 * i + 3] = f2bf(v.w);
        return;
    }
    const int wf = flat - 2560;
    const float* src;
    __bf16* dstb;
    int idx, tiles_x, N;
    if (wf < 400)      { src = Wq; dstb = WqkvT;             idx = wf;       tiles_x = 20; N = 640; }
    else if (wf < 500) { src = Wk; dstb = WqkvT + 640 * 640; idx = wf - 400; tiles_x = 5;  N = 160; }
    else if (wf < 600) { src = Wv; dstb = WqkvT + 800 * 640; idx = wf - 500; tiles_x = 5;  N = 160; }
    else               { src = Wo; dstb = WoT;               idx = wf - 600; tiles_x = 20; N = 640; }
    const int n0 = (idx % tiles_x) * 32;
    const int k0 = (idx / tiles_x) * 32;

    __shared__ float t[32][33];
    const int tx = tid & 31, ty = tid >> 5;     // 32 x 8
    #pragma unroll
    for (int i = 0; i < 4; ++i) {
        int r = ty + 8 * i;
        t[r][tx] = src[(size_t)(k0 + r) * N + n0 + tx];
    }
    __syncthreads();
    #pragma unroll
    for (int i = 0; i < 4; ++i) {
        int r = ty + 8 * i;
        dstb[(size_t)(n0 + r) * 640 + k0 + tx] = f2bf(t[tx][r]);
    }
}

// ---------------------------------------------------------------------------
// MFMA bf16 GEMM: 512 threads = 8 waves (2M x 4N), tile 128x128, macro-step
// BK=64 (two 32-wide sub-tiles in separate LDS arrays -> bank pattern of the
// verified BK=32 layout), dbuf LDS, single-step-ahead reg prefetch,
// 1 barrier per macro-step (10 for K=640). Requires K % 64 == 0.
// ---------------------------------------------------------------------------
template <typename OutT>
__global__ __launch_bounds__(512) void gemm_bf16_mfma(
    const __bf16* __restrict__ A, const __bf16* __restrict__ BT,
    OutT* __restrict__ C, int M, int N, int K, int ldc)
{
    __shared__ __bf16 As[2][2][128][40];   // [h][buf] 40960 B
    __shared__ __bf16 Bs[2][2][128][40];   // 40960 B
    const int BUFE = 128 * 40;

    const int tid  = threadIdx.x;
    const int wave = tid >> 6;
    const int lane = tid & 63;
    const int wr = wave >> 2, wc = wave & 3;
    const int l15 = lane & 15, lq = lane >> 4;
    const int m0 = blockIdx.y * 128, n0 = blockIdx.x * 128;

    f32x4 acc[4][2];
    #pragma unroll
    for (int m = 0; m < 4; ++m)
        #pragma unroll
        for (int n = 0; n < 2; ++n) acc[m][n] = (f32x4)0.0f;

    const int sArr  = tid >> 8;          // 0: stage A, 1: stage B
    const int sc    = tid & 255;
    const int srow  = sc >> 1;           // 0..127
    const int shalf = sc & 1;            // 16-col half within each 32-sub-tile
    const __bf16* gsrc = sArr ? BT : A;
    const int     grow = sArr ? n0 : m0;
    const size_t  gb   = (size_t)(grow + srow) * K + 16 * shalf;
    __bf16* ld0 = (sArr ? &Bs[0][0][0][0] : &As[0][0][0][0]) + srow * 40 + 16 * shalf;
    __bf16* ld1 = (sArr ? &Bs[1][0][0][0] : &As[1][0][0][0]) + srow * 40 + 16 * shalf;

    const int nk = K >> 6;               // macro-steps of 64

    // prologue: macro-step 0 into buffer 0
    bf16x8 r00 = *(const bf16x8*)&gsrc[gb];
    bf16x8 r01 = *(const bf16x8*)&gsrc[gb + 8];
    bf16x8 r10 = *(const bf16x8*)&gsrc[gb + 32];
    bf16x8 r11 = *(const bf16x8*)&gsrc[gb + 40];
    *(bf16x8*)ld0       = r00;
    *(bf16x8*)(ld0 + 8) = r01;
    *(bf16x8*)ld1       = r10;
    *(bf16x8*)(ld1 + 8) = r11;
    __syncthreads();

    for (int ks = 0; ks < nk; ++ks) {
        const int cur = ks & 1;
        if (ks + 1 < nk) {
            const size_t gg = gb + (size_t)(ks + 1) * 64;
            r00 = *(const bf16x8*)&gsrc[gg];
            r01 = *(const bf16x8*)&gsrc[gg + 8];
            r10 = *(const bf16x8*)&gsrc[gg + 32];
            r11 = *(const bf16x8*)&gsrc[gg + 40];
        }

        __builtin_amdgcn_s_setprio(1);
        #pragma unroll
        for (int h = 0; h < 2; ++h) {
            bf16x8 af[4], bfr[2];
            #pragma unroll
            for (int m = 0; m < 4; ++m)
                af[m] = *(const bf16x8*)&As[h][cur][wr * 64 + m * 16 + l15][8 * lq];
            #pragma unroll
            for (int n = 0; n < 2; ++n)
                bfr[n] = *(const bf16x8*)&Bs[h][cur][wc * 32 + n * 16 + l15][8 * lq];
            #pragma unroll
            for (int m = 0; m < 4; ++m)
                #pragma unroll
                for (int n = 0; n < 2; ++n)
                    acc[m][n] = __builtin_amdgcn_mfma_f32_16x16x32_bf16(af[m], bfr[n], acc[m][n], 0, 0, 0);
        }
        __builtin_amdgcn_s_setprio(0);

        if (ks + 1 < nk) {
            const int nb = (cur ^ 1) * BUFE;
            *(bf16x8*)(ld0 + nb)     = r00;
            *(bf16x8*)(ld0 + nb + 8) = r01;
            *(bf16x8*)(ld1 + nb)     = r10;
            *(bf16x8*)(ld1 + nb + 8) = r11;
        }
        __syncthreads();
    }

    #pragma unroll
    for (int m = 0; m < 4; ++m) {
        #pragma unroll
        for (int n = 0; n < 2; ++n) {
            const int col = n0 + wc * 32 + n * 16 + l15;
            if (col < N) {
                const int rbase = m0 + wr * 64 + m * 16 + 4 * lq;
                #pragma unroll
                for (int r = 0; r < 4; ++r) {
                    if constexpr (sizeof(OutT) == 2)
                        C[(size_t)(rbase + r) * ldc + col] = f2bf(acc[m][n][r]);
                    else
                        C[(size_t)(rbase + r) * ldc + col] = acc[m][n][r];
                }
            }
        }
    }
}

// ---------------------------------------------------------------------------
// Fused RMSNorm+RoPE (blocks [0,2048): 2 rows each) and V-transpose
// (blocks [2048,2688): 32x32 tiles). 256 threads.
// ---------------------------------------------------------------------------
__global__ __launch_bounds__(256) void normrope_vt_kernel(
    const unsigned short* __restrict__ qkvb, const float* __restrict__ cosb,
    const float* __restrict__ sinb, const float* __restrict__ qw,
    const float* __restrict__ kw, __bf16* __restrict__ qb,
    __bf16* __restrict__ kb, unsigned short* __restrict__ vtb)
{
    const int flat = blockIdx.x;
    const int tid  = threadIdx.x;

    __shared__ float red[4];
    __shared__ unsigned short t[32][33];

    if (flat < 2048) {
        const int half = tid >> 7;           // 0..1 -> row pair
        const int lt   = tid & 127;
        const int row  = flat * 2 + half;

        float c = 0.f, s = 0.f, wqv = 0.f, wkv = 0.f;
        if (lt < HDIM) {
            c   = cosb[(size_t)row * (HDIM / 2) + (lt >> 1)];
            s   = sinb[(size_t)row * (HDIM / 2) + (lt >> 1)];
            wqv = qw[lt];
            wkv = kw[lt];
        }
        const float sgn = (lt & 1) ? 1.0f : -1.0f;
        const float QSCALE = 0.11180339887498948f * 1.4426950408889634f;

        for (int hh = 0; hh < 10; ++hh) {
            const unsigned short* p = (hh < NH)
                ? qkvb + (size_t)row * 960 + hh * HDIM
                : qkvb + (size_t)row * 960 + HIDDEN + (hh - NH) * HDIM;
            float v = (lt < HDIM) ? bf2f(p[lt]) : 0.0f;
            float sq = v * v;
            #pragma unroll
            for (int off = 32; off; off >>= 1) sq += __shfl_down(sq, off);
            if ((lt & 63) == 0) red[half * 2 + (lt >> 6)] = sq;
            __syncthreads();
            float rms = rsqrtf((red[half * 2] + red[half * 2 + 1]) * (1.0f / HDIM) + 1e-5f);

            float w  = (hh < NH) ? wqv : wkv;
            float vn = v * rms * w;
            float vp = __shfl_xor(vn, 1);
            float o  = vn * c + sgn * vp * s;

            if (lt < HDIM) {
                if (hh < NH) qb[(size_t)row * HIDDEN + hh * HDIM + lt] = (__bf16)(o * QSCALE);
                else         kb[(size_t)row * (NKV * HDIM) + (hh - NH) * HDIM + lt] = (__bf16)o;
            }
            __syncthreads();
        }
        return;
    }

    // ---- V transpose: vtb[kvh][d][seq] ----
    const int idx = flat - 2048;             // 0..639
    const int s0 = (idx & 127) * 32;
    const int c0 = (idx >> 7) * 32;
    const int tx = tid & 31, ty = tid >> 5;  // 32 x 8
    #pragma unroll
    for (int i = 0; i < 4; ++i)
        t[ty + 8 * i][tx] = qkvb[(size_t)(s0 + ty + 8 * i) * 960 + 800 + c0 + tx];
    __syncthreads();
    #pragma unroll
    for (int i = 0; i < 4; ++i) {
        int g = c0 + ty + 8 * i;             // 0..159
        int kvh = g / HDIM, d = g % HDIM;
        vtb[((size_t)kvh * HDIM + d) * SEQ + s0 + tx] = t[tx][ty + 8 * i];
    }
}

// ---------------------------------------------------------------------------
// GQA-fused MFMA flash attention, BK=128: block = (32-query tile, kvh),
// 512 threads = 8 waves = 4 q-heads x 2 waves x 16 rows. 5-6 key tiles
// (vs 10-11 at BK=64) -> half the barrier drains / prefetch round-trips /
// shfl-chain batches. Grid (128, 2) = 256 blocks (1/CU). LDS 83.2 KB.
// Single-tile-ahead reg prefetch, exp2-domain softmax with exact
// skip-rescale (fully-masked leading tiles self-heal: later real tile
// rescales by exp2(-huge)=0). qb pre-scaled by scale*log2e.
// Schedule: [load t+1] S -> bar1 -> write K(t+1) -> softmax -> PV -> bar2
//           -> write V(t+1).
// ---------------------------------------------------------------------------
__global__ __launch_bounds__(512) void flash_attn_mfma(
    const __bf16* __restrict__ qb, const __bf16* __restrict__ kb,
    const __bf16* __restrict__ vtb, __bf16* __restrict__ attnb)
{
    const int i0   = blockIdx.x * BQG;
    const int kvh  = blockIdx.y;
    const int tid  = threadIdx.x;        // 0..511
    const int w    = tid >> 6;           // 0..7
    const int h    = kvh * 4 + (w >> 1); // q-head of this wave
    const int wsub = w & 1;              // 16-row half of the q-tile
    const int lane = tid & 63;
    const int l15  = lane & 15;
    const int lq   = lane >> 4;

    __shared__ __bf16 Ks[BK][KSTR];      // 26624 B (128 keys x 80d + pad)
    __shared__ __bf16 Vt[HDIM][VSTR];    // 21760 B (80d x 128 keys)
    __shared__ __bf16 Pl[128][VSTR];     // 34816 B (128 wave-rows x 128 keys)

    // zero K pad columns 80..95 (128 rows x 2 chunks)
    if (tid < 256) {
        int r = tid >> 1, c = HDIM + 8 * (tid & 1);
        *(float4*)&Ks[r][c] = make_float4(0.f, 0.f, 0.f, 0.f);
    }

    // staging: 1280 chunks of 8 bf16 each for K and V (chunk c = tid + 512*i)
    int koff[3], voff[3];
    __bf16* ksdst[3];
    __bf16* vsdst[3];
    bool act[3];
    #pragma unroll
    for (int i = 0; i < 3; ++i) {
        int c = tid + 512 * i;
        act[i] = (c < 1280);
        int cc = act[i] ? c : 0;
        koff[i] = (cc / 10) * (NKV * HDIM) + 8 * (cc % 10);   // key-row, d-chunk
        voff[i] = (cc >> 4) * SEQ + 8 * (cc & 15);            // d-row, key-chunk
        ksdst[i] = &Ks[cc / 10][8 * (cc % 10)];
        vsdst[i] = &Vt[cc >> 4][8 * (cc & 15)];
    }
    const __bf16* kbase = kb + kvh * HDIM;
    const __bf16* vbase = vtb + (size_t)kvh * HDIM * SEQ;

    // preload Q A-fragments (wave rows i0 + 16*wsub + l15, head h)
    bf16x8 qf[3];
    {
        const __bf16* qrow = qb + (size_t)(i0 + 16 * wsub + l15) * HIDDEN + h * HDIM;
        #pragma unroll
        for (int ks = 0; ks < 3; ++ks) {
            int off = 32 * ks + 8 * lq;
            if (off >= HDIM) off = 0;     // dummy: multiplied by zeroed K pad
            qf[ks] = *(const bf16x8*)&qrow[off];
        }
    }

    float m_i[4], l_i[4];
    f32x4 o[5];
    #pragma unroll
    for (int r = 0; r < 4; ++r) { m_i[r] = -1e30f; l_i[r] = 0.0f; }
    #pragma unroll
    for (int n = 0; n < 5; ++n) o[n] = (f32x4)0.0f;

    const int w_lo   = i0 - (WINDOW - 1);
    const int w_tile = (w_lo <= 0) ? 0 : (w_lo & ~(BK - 1));
    const int lastt  = (i0 + BQG - 1) & ~(BK - 1);
    const int n_win  = (lastt - w_tile) / BK + 1;
    const int n_tiles = n_win + ((w_tile > 0) ? 1 : 0);

    // prologue: stage tile 0
    bf16x8 krg[3], vrg[3];
    #pragma unroll
    for (int i = 0; i < 3; ++i) {
        if (act[i]) {
            krg[i] = *(const bf16x8*)&kbase[(size_t)w_tile * (NKV * HDIM) + koff[i]];
            vrg[i] = *(const bf16x8*)&vbase[(size_t)w_tile + voff[i]];
        }
    }
    #pragma unroll
    for (int i = 0; i < 3; ++i) {
        if (act[i]) {
            *(bf16x8*)ksdst[i] = krg[i];
            *(bf16x8*)vsdst[i] = vrg[i];
        }
    }
    __syncthreads();

    for (int t = 0; t < n_tiles; ++t) {
        const int j0 = (t < n_win) ? (w_tile + t * BK) : 0;
        const bool more = (t + 1 < n_tiles);

        // ---- prefetch next tile into registers ----
        if (more) {
            const int j1 = (t + 1 < n_win) ? (w_tile + (t + 1) * BK) : 0;
            #pragma unroll
            for (int i = 0; i < 3; ++i) {
                if (act[i]) {
                    krg[i] = *(const bf16x8*)&kbase[(size_t)j1 * (NKV * HDIM) + koff[i]];
                    vrg[i] = *(const bf16x8*)&vbase[(size_t)j1 + voff[i]];
                }
            }
        }

        // ---- S = Q K^T : 24 MFMA per wave ----
        f32x4 sacc[8];
        #pragma unroll
        for (int n = 0; n < 8; ++n) sacc[n] = (f32x4)0.0f;
        __builtin_amdgcn_s_setprio(1);
        #pragma unroll
        for (int ks = 0; ks < 3; ++ks) {
            #pragma unroll
            for (int n = 0; n < 8; ++n) {
                bf16x8 kf = *(const bf16x8*)&Ks[n * 16 + l15][32 * ks + 8 * lq];
                sacc[n] = __builtin_amdgcn_mfma_f32_16x16x32_bf16(qf[ks], kf, sacc[n], 0, 0, 0);
            }
        }
        __builtin_amdgcn_s_setprio(0);

        __syncthreads();                    // bar1: S reads of Ks done
        if (more) {
            #pragma unroll
            for (int i = 0; i < 3; ++i)
                if (act[i]) *(bf16x8*)ksdst[i] = krg[i];
        }

        // ---- mask (full ⟺ i0-480 <= j0 <= i0-128) ----
        const bool full = (j0 >= i0 - 480) && (j0 <= i0 - 128);
        if (!full) {
            #pragma unroll
            for (int n = 0; n < 8; ++n) {
                int j = j0 + 16 * n + l15;
                #pragma unroll
                for (int r = 0; r < 4; ++r) {
                    int i = i0 + 16 * wsub + 4 * lq + r;
                    bool allowed = (j <= i) && ((j >= i - (WINDOW - 1)) || (j < SINK));
                    if (!allowed) sacc[n][r] = -1e30f;
                }
            }
        }

        // ---- online softmax (exp2 domain, exact skip-rescale) ----
        #pragma unroll
        for (int r = 0; r < 4; ++r) {
            float rmax = sacc[0][r];
            #pragma unroll
            for (int n = 1; n < 8; ++n) rmax = fmaxf(rmax, sacc[n][r]);
            rmax = fmaxf(rmax, __shfl_xor(rmax, 1));
            rmax = fmaxf(rmax, __shfl_xor(rmax, 2));
            rmax = fmaxf(rmax, __shfl_xor(rmax, 4));
            rmax = fmaxf(rmax, __shfl_xor(rmax, 8));
            if (rmax > m_i[r]) {
                float alpha = fexp2(m_i[r] - rmax);
                m_i[r] = rmax;
                l_i[r] *= alpha;
                #pragma unroll
                for (int n = 0; n < 5; ++n) o[n][r] *= alpha;
            }
            float rsum = 0.0f;
            #pragma unroll
            for (int n = 0; n < 8; ++n) {
                float pe = fexp2(sacc[n][r] - m_i[r]);
                Pl[16 * w + 4 * lq + r][16 * n + l15] = (__bf16)pe;
                rsum += pe;
            }
            rsum += __shfl_xor(rsum, 1);
            rsum += __shfl_xor(rsum, 2);
            rsum += __shfl_xor(rsum, 4);
            rsum += __shfl_xor(rsum, 8);
            l_i[r] += rsum;
        }

        // ---- O += P V : wave-private P rows, 20 MFMA per wave ----
        __builtin_amdgcn_s_setprio(1);
        #pragma unroll
        for (int ks = 0; ks < 4; ++ks) {
            bf16x8 pf = *(const bf16x8*)&Pl[16 * w + l15][32 * ks + 8 * lq];
            #pragma unroll
            for (int n = 0; n < 5; ++n) {
                bf16x8 vf = *(const bf16x8*)&Vt[16 * n + l15][32 * ks + 8 * lq];
                o[n] = __builtin_amdgcn_mfma_f32_16x16x32_bf16(pf, vf, o[n], 0, 0, 0);
            }
        }
        __builtin_amdgcn_s_setprio(0);

        __syncthreads();                    // bar2: PV reads of Vt done
        if (more) {
            #pragma unroll
            for (int i = 0; i < 3; ++i)
                if (act[i]) *(bf16x8*)vsdst[i] = vrg[i];
        }
    }

    // ---- epilogue ----
    #pragma unroll
    for (int r = 0; r < 4; ++r) {
        float inv = 1.0f / l_i[r];
        int row = i0 + 16 * wsub + 4 * lq + r;
        #pragma unroll
        for (int n = 0; n < 5; ++n)
            attnb[(size_t)row * HIDDEN + h * HDIM + 16 * n + l15] = (__bf16)(o[n][r] * inv);
    }
}

// ---------------------------------------------------------------------------
extern "C" void kernel_launch(void* const* d_in, const int* in_sizes, int n_in,
                              void* d_out, int out_size, void* d_ws, size_t ws_size,
                              hipStream_t stream)
{
    const float* x    = (const float*)d_in[0];
    const float* cosb = (const float*)d_in[1];
    const float* sinb = (const float*)d_in[2];
    const float* Wq   = (const float*)d_in[3];
    const float* Wk   = (const float*)d_in[4];
    const float* Wv   = (const float*)d_in[5];
    const float* Wo   = (const float*)d_in[6];
    const float* qw   = (const float*)d_in[7];
    const float* kw   = (const float*)d_in[8];
    float* out = (float*)d_out;

    char* ws = (char*)d_ws;
    __bf16* qkvb  = (__bf16*)ws;                                 // [4096][960]
    __bf16* xb    = qkvb + (size_t)SEQ * 960;                    // [4096][640] -> attnb
    __bf16* qb    = xb   + (size_t)SEQ * HIDDEN;                 // [4096][640]
    __bf16* kb    = qb   + (size_t)SEQ * HIDDEN;                 // [4096][160]
    __bf16* vtb   = kb   + (size_t)SEQ * 160;                    // [2][80][4096]
    __bf16* WqkvT = vtb  + (size_t)2 * HDIM * SEQ;               // [1024][640]
    __bf16* WoT   = WqkvT + (size_t)1024 * HIDDEN;               // [640][640]

    prep_kernel<<<dim3(3560), dim3(256), 0, stream>>>(
        x, Wq, Wk, Wv, Wo, xb, WqkvT, WoT);

    gemm_bf16_mfma<__bf16><<<dim3(8, SEQ / 128), dim3(512), 0, stream>>>(
        xb, WqkvT, qkvb, SEQ, 960, HIDDEN, 960);

    normrope_vt_kernel<<<dim3(2688), dim3(256), 0, stream>>>(
        (const unsigned short*)qkvb, cosb, sinb, qw, kw, qb, kb,
        (unsigned short*)vtb);

    flash_attn_mfma<<<dim3(SEQ / BQG, NKV), dim3(512), 0, stream>>>(
        qb, kb, vtb, xb);

    gemm_bf16_mfma<float><<<dim3(HIDDEN / 128, SEQ / 128), dim3(512), 0, stream>>>(
        xb, WoT, out, SEQ, HIDDEN, HIDDEN, HIDDEN);
}